// Round 5
// baseline (537.898 us; speedup 1.0000x reference)
//
#include <hip/hip_runtime.h>
#include <hip/hip_bf16.h>
#include <cstdint>

// Problem shapes (fixed)
#define B_     2
#define N_     2048
#define DIM_   1024
#define H_     16
#define DH_    64
#define MEM_   2048
#define JT_    4096      // MEM_ + N_
#define INNER_ 1024
#define SCALE_ 0.125f

typedef float f32x4 __attribute__((ext_vector_type(4)));
typedef short s16x8 __attribute__((ext_vector_type(8)));
typedef short s16x4 __attribute__((ext_vector_type(4)));

__device__ __forceinline__ short bf16_of(float f) {
    __hip_bfloat16 h = __float2bfloat16(f);   // RNE
    return *(short*)&h;
}

__device__ __forceinline__ void gload16(const void* g, short* l) {
    __builtin_amdgcn_global_load_lds(
        (const __attribute__((address_space(1))) unsigned int*)g,
        (__attribute__((address_space(3))) unsigned int*)l, 16, 0, 0);
}

// ---------------------------------------------------------------------------
// Kernel A: cast x fp32 [4096][1024] -> xb bf16 (row-major)
// ---------------------------------------------------------------------------
__global__ __launch_bounds__(256) void cast_x(
    const float* __restrict__ x, short* __restrict__ xb)
{
    const int total4 = B_ * N_ * DIM_ / 4;   // 1M
    for (int idx = blockIdx.x * blockDim.x + threadIdx.x; idx < total4;
         idx += gridDim.x * blockDim.x) {
        float4 v = ((const float4*)x)[idx];
        s16x4 o;
        o[0] = bf16_of(v.x); o[1] = bf16_of(v.y);
        o[2] = bf16_of(v.z); o[3] = bf16_of(v.w);
        *(s16x4*)&xb[idx * 4] = o;
    }
}

// ---------------------------------------------------------------------------
// Kernel B: transpose-cast weights -> Wt bf16 [3072][1024], Wt[n][k]=W[k][n].
// SCALE folded into q columns (n<1024).
// ---------------------------------------------------------------------------
__global__ __launch_bounds__(256) void cast_w(
    const float* __restrict__ Wq, const float* __restrict__ Wkv,
    short* __restrict__ Wt)
{
    const int kt = blockIdx.x;   // 0..15
    const int nt = blockIdx.y;   // 0..47
    __shared__ float tile[64][65];   // [n_local][k_local]
    const int t = threadIdx.x;
    const int r = t >> 2, s4 = (t & 3) * 16;

    const int n0 = nt * 64;
    const float* src;
    int ldn, nc0;
    if (n0 < 1024) { src = Wq;  ldn = 1024; nc0 = n0; }
    else           { src = Wkv; ldn = 2048; nc0 = n0 - 1024; }
    const float scale = (n0 < 1024) ? SCALE_ : 1.0f;

#pragma unroll
    for (int kq = 0; kq < 4; ++kq) {
        float4 v = *(const float4*)&src[(size_t)(kt * 64 + r) * ldn + nc0 + s4 + kq * 4];
        tile[s4 + kq * 4 + 0][r] = v.x;
        tile[s4 + kq * 4 + 1][r] = v.y;
        tile[s4 + kq * 4 + 2][r] = v.z;
        tile[s4 + kq * 4 + 3][r] = v.w;
    }
    __syncthreads();
    short ov[16];
#pragma unroll
    for (int e = 0; e < 16; ++e) ov[e] = bf16_of(tile[r][s4 + e] * scale);
    short* dst = &Wt[(size_t)(n0 + r) * 1024 + kt * 64 + s4];
    *(s16x8*)&dst[0] = *(s16x8*)&ov[0];
    *(s16x8*)&dst[8] = *(s16x8*)&ov[8];
}

// ---------------------------------------------------------------------------
// Kernel C: MFMA projection GEMM (unchanged).
// ---------------------------------------------------------------------------
#define PLDC 152

__global__ __launch_bounds__(256) void mfma_proj(
    const short* __restrict__ Wt, const short* __restrict__ xb,
    short* __restrict__ qbuf, short* __restrict__ kbuf, short* __restrict__ vtbuf)
{
    const int bc = blockIdx.x;
    const int bi = blockIdx.y;
    const int tid = threadIdx.x;
    const int w = tid >> 6, lane = tid & 63, g = lane >> 4, li = lane & 15;
    const int wr = w >> 1, wc = w & 1;

    __shared__ short smem[128 * PLDC];
    short* A_lds = smem;
    short* B_lds = smem + 8192;

    f32x4 acc[4][4];
#pragma unroll
    for (int m = 0; m < 4; ++m)
#pragma unroll
        for (int n = 0; n < 4; ++n) acc[m][n] = f32x4{0.f, 0.f, 0.f, 0.f};

    const size_t arow0 = (size_t)bc * 128;
    const size_t brow0 = (size_t)bi * 128;

    for (int t = 0; t < 16; ++t) {
        __syncthreads();
#pragma unroll
        for (int u = 0; u < 4; ++u) {
            const int c = (w * 4 + u) * 64 + lane;
            const int row = c >> 3, q = c & 7;
            const int qs = q ^ (row & 7);
            gload16(&Wt[(arow0 + row) * 1024 + t * 64 + qs * 8],
                    &A_lds[(w * 4 + u) * 512 + lane * 8]);
            gload16(&xb[(brow0 + row) * 1024 + t * 64 + qs * 8],
                    &B_lds[(w * 4 + u) * 512 + lane * 8]);
        }
        __syncthreads();
#pragma unroll
        for (int kc = 0; kc < 2; ++kc) {
            s16x8 af[4], bf[4];
#pragma unroll
            for (int mt = 0; mt < 4; ++mt) {
                const int row = wr * 64 + mt * 16 + li;
                af[mt] = *(const s16x8*)&A_lds[row * 64 + ((kc * 4 + g) ^ (row & 7)) * 8];
            }
#pragma unroll
            for (int nt = 0; nt < 4; ++nt) {
                const int row = wc * 64 + nt * 16 + li;
                bf[nt] = *(const s16x8*)&B_lds[row * 64 + ((kc * 4 + g) ^ (row & 7)) * 8];
            }
#pragma unroll
            for (int mt = 0; mt < 4; ++mt)
#pragma unroll
                for (int nt = 0; nt < 4; ++nt)
                    acc[mt][nt] = __builtin_amdgcn_mfma_f32_16x16x32_bf16(af[mt], bf[nt], acc[mt][nt], 0, 0, 0);
        }
    }

    __syncthreads();
    const int c0 = bc * 128;
    const int i0g = bi * 128;
    const int b = i0g >> 11;
    const int ii0 = i0g & 2047;

    if (c0 < 2048) {
#pragma unroll
        for (int mt = 0; mt < 4; ++mt)
#pragma unroll
            for (int nt = 0; nt < 4; ++nt) {
                const int i_l = wc * 64 + nt * 16 + li;
                const int c_l = wr * 64 + mt * 16 + g * 4;
                s16x4 v4;
                v4[0] = bf16_of(acc[mt][nt][0]);
                v4[1] = bf16_of(acc[mt][nt][1]);
                v4[2] = bf16_of(acc[mt][nt][2]);
                v4[3] = bf16_of(acc[mt][nt][3]);
                *(s16x4*)&smem[i_l * PLDC + c_l] = v4;
            }
        __syncthreads();
        const bool isq = (c0 < 1024);
#pragma unroll
        for (int u = 0; u < 8; ++u) {
            const int ch = tid + u * 256;
            const int i_l = ch >> 4, seg = ch & 15;
            s16x8 v = *(const s16x8*)&smem[i_l * PLDC + seg * 8];
            const int cg = c0 + seg * 8;
            const int h = (cg >> 6) & 15;
            const int d = cg & 63;
            if (isq)
                *(s16x8*)&qbuf[(((size_t)(b * H_ + h)) * N_ + ii0 + i_l) * DH_ + d] = v;
            else
                *(s16x8*)&kbuf[(((size_t)(b * H_ + h)) * JT_ + MEM_ + ii0 + i_l) * DH_ + d] = v;
        }
    } else {
#pragma unroll
        for (int mt = 0; mt < 4; ++mt)
#pragma unroll
            for (int nt = 0; nt < 4; ++nt) {
                const int i_l = wc * 64 + nt * 16 + li;
                const int c_b = wr * 64 + mt * 16 + g * 4;
#pragma unroll
                for (int r = 0; r < 4; ++r)
                    smem[(c_b + r) * PLDC + i_l] = bf16_of(acc[mt][nt][r]);
            }
        __syncthreads();
#pragma unroll
        for (int u = 0; u < 8; ++u) {
            const int ch = tid + u * 256;
            const int c_l = ch >> 4, seg = ch & 15;
            s16x8 v = *(const s16x8*)&smem[c_l * PLDC + seg * 8];
            const int cv = c0 + c_l - 2048;
            const int h = cv >> 6, d = cv & 63;
            *(s16x8*)&vtbuf[(((size_t)(b * H_ + h)) * DH_ + d) * JT_ + MEM_ + ii0 + seg * 8] = v;
        }
    }
}

// ---------------------------------------------------------------------------
// Kernel D: mem_k fp32 [b][j][h*64+d] -> kbuf bf16 [b][h][j][d], j<2048
// ---------------------------------------------------------------------------
__global__ __launch_bounds__(256) void copymem_k(
    const float* __restrict__ mem_k, short* __restrict__ kbuf)
{
    const int total4 = B_ * MEM_ * INNER_ / 4;
    for (int idx = blockIdx.x * blockDim.x + threadIdx.x; idx < total4;
         idx += gridDim.x * blockDim.x) {
        const int flat = idx * 4;
        const int c = flat & 1023;
        const int j = (flat >> 10) & 2047;
        const int b = flat >> 21;
        const int h = c >> 6, d = c & 63;
        float4 v = ((const float4*)mem_k)[idx];
        s16x4 o;
        o[0] = bf16_of(v.x); o[1] = bf16_of(v.y);
        o[2] = bf16_of(v.z); o[3] = bf16_of(v.w);
        *(s16x4*)&kbuf[(((size_t)(b * H_ + h)) * JT_ + j) * DH_ + d] = o;
    }
}

// ---------------------------------------------------------------------------
// Kernel E: mem_v fp32 [b][j][h*64+d] -> vtbuf bf16 [b][h][d][j], j<2048
// ---------------------------------------------------------------------------
__global__ __launch_bounds__(256) void transpose_memv(
    const float* __restrict__ mem_v, short* __restrict__ vtbuf)
{
    const int jt = blockIdx.x, h = blockIdx.y, b = blockIdx.z;
    const int j0 = jt * 64;
    __shared__ float tile[64][65];
    const int t = threadIdx.x;
    const int r = t >> 2, s4 = (t & 3) * 16;
#pragma unroll
    for (int k = 0; k < 4; ++k) {
        float4 v = *(const float4*)&mem_v[((size_t)(b * MEM_ + j0 + r)) * INNER_ + h * DH_ + s4 + k * 4];
        tile[s4 + k * 4 + 0][r] = v.x;
        tile[s4 + k * 4 + 1][r] = v.y;
        tile[s4 + k * 4 + 2][r] = v.z;
        tile[s4 + k * 4 + 3][r] = v.w;
    }
    __syncthreads();
    short ov[16];
#pragma unroll
    for (int e = 0; e < 16; ++e) ov[e] = bf16_of(tile[r][s4 + e]);
    short* dst = &vtbuf[((size_t)((b * H_ + h) * DH_ + r)) * JT_ + j0 + s4];
    *(s16x8*)&dst[0] = *(s16x8*)&ov[0];
    *(s16x8*)&dst[8] = *(s16x8*)&ov[8];
}

// ---------------------------------------------------------------------------
// Kernel F: flash attention, bf16 MFMA. v2:
//  - 512 threads = 8 waves, wave owns 16 q-rows (4 waves/SIMD occupancy)
//  - double-buffered K/V LDS with async-STAGE split (loads issued before
//    compute of current tile; LDS write after barrier)
//  - remap: lid%8 groups (h,b)-twins per XCD; lid and lid+256 (same CU)
//    get complementary zt so per-CU tile count is constant (34+2zt pairs->98)
// ---------------------------------------------------------------------------
#define LDK 72
#define LDP 72

__global__ __launch_bounds__(512) void attn_flash(
    const short* __restrict__ qbuf, const short* __restrict__ kbuf,
    const short* __restrict__ vtbuf, const float* __restrict__ pos_bias,
    float* __restrict__ out)
{
    const int lid = blockIdx.x;                       // 0..511
    const int k_  = lid & 255;
    const int hi  = lid >> 8;
    const int h   = (k_ & 7) | (((k_ >> 3) & 1) << 3);
    const int b   = (k_ >> 4) & 1;
    const int ztl = k_ >> 5;                          // 0..7
    const int zt  = hi ? (15 - ztl) : ztl;            // balanced pairing
    const int i0  = zt * 128;

    const int tid = threadIdx.x;
    const int w = tid >> 6, lane = tid & 63, g = lane >> 4, li = lane & 15;

    __shared__ short K_lds[2][64 * LDK];
    __shared__ short VT_lds[2][64 * LDK];
    __shared__ short P_lds[8][16 * LDP];

    const size_t bh = b * H_ + h;
    const short* kg  = kbuf  + bh * (size_t)JT_ * DH_;
    const short* vtg = vtbuf + bh * (size_t)DH_ * JT_;
    const float* pb  = pos_bias + (size_t)h * N_ * JT_;

    // Q fragments: wave w owns q-rows [i0+w*16, i0+w*16+16)
    s16x8 aq[2];
#pragma unroll
    for (int kc = 0; kc < 2; ++kc)
        aq[kc] = *(const s16x8*)&qbuf[(bh * N_ + i0 + w * 16 + li) * DH_ + kc * 32 + g * 8];

    f32x4 o[4];
    float m_run[4], l_run[4];
#pragma unroll
    for (int dt = 0; dt < 4; ++dt) o[dt] = f32x4{0.f, 0.f, 0.f, 0.f};
#pragma unroll
    for (int r = 0; r < 4; ++r) { m_run[r] = -3.0e38f; l_run[r] = 0.f; }

    const int ntiles = 34 + 2 * zt;
    const int row = tid >> 3, seg = tid & 7;   // staging: 512 chunks of 8 bf16

    // prologue: stage tile 0 into buffer 0
    {
        s16x8 kv = *(const s16x8*)&kg[(size_t)row * DH_ + seg * 8];
        s16x8 vv = *(const s16x8*)&vtg[(size_t)row * JT_ + seg * 8];
        *(s16x8*)&K_lds[0][row * LDK + seg * 8] = kv;
        *(s16x8*)&VT_lds[0][row * LDK + seg * 8] = vv;
    }
    __syncthreads();

    for (int t = 0; t < ntiles; ++t) {
        const int cur = t & 1;
        const int j0 = t * 64;

        // ---- async-STAGE: issue next tile's loads before compute ----
        s16x8 kreg, vreg;
        if (t + 1 < ntiles) {
            kreg = *(const s16x8*)&kg[(size_t)(j0 + 64 + row) * DH_ + seg * 8];
            vreg = *(const s16x8*)&vtg[(size_t)row * JT_ + j0 + 64 + seg * 8];
        }

        // ---- S = Q K^T ----
        f32x4 sacc[4];
#pragma unroll
        for (int nt = 0; nt < 4; ++nt) sacc[nt] = f32x4{0.f, 0.f, 0.f, 0.f};
#pragma unroll
        for (int kc = 0; kc < 2; ++kc)
#pragma unroll
            for (int nt = 0; nt < 4; ++nt) {
                s16x8 bk = *(const s16x8*)&K_lds[cur][(nt * 16 + li) * LDK + kc * 32 + g * 8];
                sacc[nt] = __builtin_amdgcn_mfma_f32_16x16x32_bf16(aq[kc], bk, sacc[nt], 0, 0, 0);
            }

        // ---- bias + mask + online softmax ----
        const int qrb = i0 + w * 16 + g * 4;     // + r = global i
        float s[4][4];
#pragma unroll
        for (int nt = 0; nt < 4; ++nt) {
            const int jg = j0 + nt * 16 + li;
#pragma unroll
            for (int r = 0; r < 4; ++r) {
                float sv = sacc[nt][r] + pb[(size_t)(qrb + r) * JT_ + jg];
                s[nt][r] = (jg > MEM_ + qrb + r) ? -1e30f : sv;
            }
        }
        float sc[4];
#pragma unroll
        for (int r = 0; r < 4; ++r) {
            float tm = fmaxf(fmaxf(s[0][r], s[1][r]), fmaxf(s[2][r], s[3][r]));
            tm = fmaxf(tm, __shfl_xor(tm, 1));
            tm = fmaxf(tm, __shfl_xor(tm, 2));
            tm = fmaxf(tm, __shfl_xor(tm, 4));
            tm = fmaxf(tm, __shfl_xor(tm, 8));
            const float m_new = fmaxf(m_run[r], tm);
            sc[r] = __expf(m_run[r] - m_new);
            m_run[r] = m_new;
        }
#pragma unroll
        for (int nt = 0; nt < 4; ++nt)
#pragma unroll
            for (int r = 0; r < 4; ++r)
                s[nt][r] = __expf(s[nt][r] - m_run[r]);
#pragma unroll
        for (int r = 0; r < 4; ++r) {
            float ts = s[0][r] + s[1][r] + s[2][r] + s[3][r];
            ts += __shfl_xor(ts, 1);
            ts += __shfl_xor(ts, 2);
            ts += __shfl_xor(ts, 4);
            ts += __shfl_xor(ts, 8);
            l_run[r] = l_run[r] * sc[r] + ts;
#pragma unroll
            for (int dt = 0; dt < 4; ++dt) o[dt][r] *= sc[r];
        }
#pragma unroll
        for (int nt = 0; nt < 4; ++nt)
#pragma unroll
            for (int r = 0; r < 4; ++r)
                P_lds[w][(g * 4 + r) * LDP + nt * 16 + li] = bf16_of(s[nt][r]);

        // ---- O += P V ----
#pragma unroll
        for (int kc = 0; kc < 2; ++kc) {
            s16x8 pa = *(const s16x8*)&P_lds[w][li * LDP + kc * 32 + g * 8];
#pragma unroll
            for (int dt = 0; dt < 4; ++dt) {
                s16x8 bv = *(const s16x8*)&VT_lds[cur][(dt * 16 + li) * LDK + kc * 32 + g * 8];
                o[dt] = __builtin_amdgcn_mfma_f32_16x16x32_bf16(pa, bv, o[dt], 0, 0, 0);
            }
        }

        __syncthreads();
        // ---- write staged regs into the other buffer ----
        if (t + 1 < ntiles) {
            *(s16x8*)&K_lds[cur ^ 1][row * LDK + seg * 8] = kreg;
            *(s16x8*)&VT_lds[cur ^ 1][row * LDK + seg * 8] = vreg;
        }
        __syncthreads();
    }

    // ---- epilogue: out[b][i][h*64+d] = o / l ----
#pragma unroll
    for (int r = 0; r < 4; ++r) {
        const int i = i0 + w * 16 + g * 4 + r;
        const float rinv = 1.0f / l_run[r];
#pragma unroll
        for (int dt = 0; dt < 4; ++dt)
            out[((size_t)(b * N_ + i)) * INNER_ + h * DH_ + dt * 16 + li] = o[dt][r] * rinv;
    }
}

// ---------------------------------------------------------------------------
extern "C" void kernel_launch(void* const* d_in, const int* in_sizes, int n_in,
                              void* d_out, int out_size, void* d_ws, size_t ws_size,
                              hipStream_t stream)
{
    const float* x        = (const float*)d_in[0];
    const float* mem_k    = (const float*)d_in[1];
    const float* mem_v    = (const float*)d_in[2];
    const float* pos_bias = (const float*)d_in[3];
    const float* Wq       = (const float*)d_in[4];
    const float* Wkv      = (const float*)d_in[5];
    float* out = (float*)d_out;

    // workspace layout:
    //   qbuf  bf16  8 MiB   [b][h][i][64]
    //   kbuf  bf16 16 MiB   [b][h][j][64]
    //   vtbuf bf16 16 MiB   [b][h][d][j]
    //   xb    bf16  8 MiB   [4096][1024]
    //   Wt    bf16  6 MiB   [3072][1024]
    char* ws = (char*)d_ws;
    short* qbuf  = (short*)(ws);
    short* kbuf  = (short*)(ws + (8u << 20));
    short* vtbuf = (short*)(ws + (24u << 20));
    short* xb    = (short*)(ws + (40u << 20));
    short* Wt    = (short*)(ws + (48u << 20));

    cast_x<<<2048, 256, 0, stream>>>(x, xb);
    cast_w<<<dim3(16, 48), 256, 0, stream>>>(Wq, Wkv, Wt);
    copymem_k<<<2048, 256, 0, stream>>>(mem_k, kbuf);
    transpose_memv<<<dim3(32, H_, B_), 256, 0, stream>>>(mem_v, vtbuf);

    mfma_proj<<<dim3(24, 32), 256, 0, stream>>>(Wt, xb, qbuf, kbuf, vtbuf);

    attn_flash<<<512, 512, 0, stream>>>(qbuf, kbuf, vtbuf, pos_bias, out);
}

// Round 6
// 314.225 us; speedup vs baseline: 1.7118x; 1.7118x over previous
//
#include <hip/hip_runtime.h>
#include <hip/hip_bf16.h>
#include <cstdint>

// Problem shapes (fixed)
#define B_     2
#define N_     2048
#define DIM_   1024
#define H_     16
#define DH_    64
#define MEM_   2048
#define JT_    4096      // MEM_ + N_
#define INNER_ 1024
#define SCALE_ 0.125f

typedef float f32x4 __attribute__((ext_vector_type(4)));
typedef short s16x8 __attribute__((ext_vector_type(8)));
typedef short s16x4 __attribute__((ext_vector_type(4)));

__device__ __forceinline__ short bf16_of(float f) {
    __hip_bfloat16 h = __float2bfloat16(f);   // RNE
    return *(short*)&h;
}

__device__ __forceinline__ void gload16(const void* g, short* l) {
    __builtin_amdgcn_global_load_lds(
        (const __attribute__((address_space(1))) unsigned int*)g,
        (__attribute__((address_space(3))) unsigned int*)l, 16, 0, 0);
}

// ---------------------------------------------------------------------------
// Kernel A: cast x fp32 [4096][1024] -> xb bf16 (row-major)
// ---------------------------------------------------------------------------
__global__ __launch_bounds__(256) void cast_x(
    const float* __restrict__ x, short* __restrict__ xb)
{
    const int total4 = B_ * N_ * DIM_ / 4;   // 1M
    for (int idx = blockIdx.x * blockDim.x + threadIdx.x; idx < total4;
         idx += gridDim.x * blockDim.x) {
        float4 v = ((const float4*)x)[idx];
        s16x4 o;
        o[0] = bf16_of(v.x); o[1] = bf16_of(v.y);
        o[2] = bf16_of(v.z); o[3] = bf16_of(v.w);
        *(s16x4*)&xb[idx * 4] = o;
    }
}

// ---------------------------------------------------------------------------
// Kernel B: transpose-cast weights -> Wt bf16 [3072][1024], Wt[n][k]=W[k][n].
// SCALE folded into q columns (n<1024).
// ---------------------------------------------------------------------------
__global__ __launch_bounds__(256) void cast_w(
    const float* __restrict__ Wq, const float* __restrict__ Wkv,
    short* __restrict__ Wt)
{
    const int kt = blockIdx.x;   // 0..15
    const int nt = blockIdx.y;   // 0..47
    __shared__ float tile[64][65];   // [n_local][k_local]
    const int t = threadIdx.x;
    const int r = t >> 2, s4 = (t & 3) * 16;

    const int n0 = nt * 64;
    const float* src;
    int ldn, nc0;
    if (n0 < 1024) { src = Wq;  ldn = 1024; nc0 = n0; }
    else           { src = Wkv; ldn = 2048; nc0 = n0 - 1024; }
    const float scale = (n0 < 1024) ? SCALE_ : 1.0f;

#pragma unroll
    for (int kq = 0; kq < 4; ++kq) {
        float4 v = *(const float4*)&src[(size_t)(kt * 64 + r) * ldn + nc0 + s4 + kq * 4];
        tile[s4 + kq * 4 + 0][r] = v.x;
        tile[s4 + kq * 4 + 1][r] = v.y;
        tile[s4 + kq * 4 + 2][r] = v.z;
        tile[s4 + kq * 4 + 3][r] = v.w;
    }
    __syncthreads();
    short ov[16];
#pragma unroll
    for (int e = 0; e < 16; ++e) ov[e] = bf16_of(tile[r][s4 + e] * scale);
    short* dst = &Wt[(size_t)(n0 + r) * 1024 + kt * 64 + s4];
    *(s16x8*)&dst[0] = *(s16x8*)&ov[0];
    *(s16x8*)&dst[8] = *(s16x8*)&ov[8];
}

// ---------------------------------------------------------------------------
// Kernel C: MFMA projection GEMM (unchanged from passing rounds 3-5).
// ---------------------------------------------------------------------------
#define PLDC 152

__global__ __launch_bounds__(256) void mfma_proj(
    const short* __restrict__ Wt, const short* __restrict__ xb,
    short* __restrict__ qbuf, short* __restrict__ kbuf, short* __restrict__ vtbuf)
{
    const int bc = blockIdx.x;
    const int bi = blockIdx.y;
    const int tid = threadIdx.x;
    const int w = tid >> 6, lane = tid & 63, g = lane >> 4, li = lane & 15;
    const int wr = w >> 1, wc = w & 1;

    __shared__ short smem[128 * PLDC];
    short* A_lds = smem;
    short* B_lds = smem + 8192;

    f32x4 acc[4][4];
#pragma unroll
    for (int m = 0; m < 4; ++m)
#pragma unroll
        for (int n = 0; n < 4; ++n) acc[m][n] = f32x4{0.f, 0.f, 0.f, 0.f};

    const size_t arow0 = (size_t)bc * 128;
    const size_t brow0 = (size_t)bi * 128;

    for (int t = 0; t < 16; ++t) {
        __syncthreads();
#pragma unroll
        for (int u = 0; u < 4; ++u) {
            const int c = (w * 4 + u) * 64 + lane;
            const int row = c >> 3, q = c & 7;
            const int qs = q ^ (row & 7);
            gload16(&Wt[(arow0 + row) * 1024 + t * 64 + qs * 8],
                    &A_lds[(w * 4 + u) * 512 + lane * 8]);
            gload16(&xb[(brow0 + row) * 1024 + t * 64 + qs * 8],
                    &B_lds[(w * 4 + u) * 512 + lane * 8]);
        }
        __syncthreads();
#pragma unroll
        for (int kc = 0; kc < 2; ++kc) {
            s16x8 af[4], bf[4];
#pragma unroll
            for (int mt = 0; mt < 4; ++mt) {
                const int row = wr * 64 + mt * 16 + li;
                af[mt] = *(const s16x8*)&A_lds[row * 64 + ((kc * 4 + g) ^ (row & 7)) * 8];
            }
#pragma unroll
            for (int nt = 0; nt < 4; ++nt) {
                const int row = wc * 64 + nt * 16 + li;
                bf[nt] = *(const s16x8*)&B_lds[row * 64 + ((kc * 4 + g) ^ (row & 7)) * 8];
            }
#pragma unroll
            for (int mt = 0; mt < 4; ++mt)
#pragma unroll
                for (int nt = 0; nt < 4; ++nt)
                    acc[mt][nt] = __builtin_amdgcn_mfma_f32_16x16x32_bf16(af[mt], bf[nt], acc[mt][nt], 0, 0, 0);
        }
    }

    __syncthreads();
    const int c0 = bc * 128;
    const int i0g = bi * 128;
    const int b = i0g >> 11;
    const int ii0 = i0g & 2047;

    if (c0 < 2048) {
#pragma unroll
        for (int mt = 0; mt < 4; ++mt)
#pragma unroll
            for (int nt = 0; nt < 4; ++nt) {
                const int i_l = wc * 64 + nt * 16 + li;
                const int c_l = wr * 64 + mt * 16 + g * 4;
                s16x4 v4;
                v4[0] = bf16_of(acc[mt][nt][0]);
                v4[1] = bf16_of(acc[mt][nt][1]);
                v4[2] = bf16_of(acc[mt][nt][2]);
                v4[3] = bf16_of(acc[mt][nt][3]);
                *(s16x4*)&smem[i_l * PLDC + c_l] = v4;
            }
        __syncthreads();
        const bool isq = (c0 < 1024);
#pragma unroll
        for (int u = 0; u < 8; ++u) {
            const int ch = tid + u * 256;
            const int i_l = ch >> 4, seg = ch & 15;
            s16x8 v = *(const s16x8*)&smem[i_l * PLDC + seg * 8];
            const int cg = c0 + seg * 8;
            const int h = (cg >> 6) & 15;
            const int d = cg & 63;
            if (isq)
                *(s16x8*)&qbuf[(((size_t)(b * H_ + h)) * N_ + ii0 + i_l) * DH_ + d] = v;
            else
                *(s16x8*)&kbuf[(((size_t)(b * H_ + h)) * JT_ + MEM_ + ii0 + i_l) * DH_ + d] = v;
        }
    } else {
#pragma unroll
        for (int mt = 0; mt < 4; ++mt)
#pragma unroll
            for (int nt = 0; nt < 4; ++nt) {
                const int i_l = wc * 64 + nt * 16 + li;
                const int c_b = wr * 64 + mt * 16 + g * 4;
#pragma unroll
                for (int r = 0; r < 4; ++r)
                    smem[(c_b + r) * PLDC + i_l] = bf16_of(acc[mt][nt][r]);
            }
        __syncthreads();
#pragma unroll
        for (int u = 0; u < 8; ++u) {
            const int ch = tid + u * 256;
            const int c_l = ch >> 4, seg = ch & 15;
            s16x8 v = *(const s16x8*)&smem[c_l * PLDC + seg * 8];
            const int cv = c0 + c_l - 2048;
            const int h = cv >> 6, d = cv & 63;
            *(s16x8*)&vtbuf[(((size_t)(b * H_ + h)) * DH_ + d) * JT_ + MEM_ + ii0 + seg * 8] = v;
        }
    }
}

// ---------------------------------------------------------------------------
// Kernel D: mem_k fp32 [b][j][h*64+d] -> kbuf bf16 [b][h][j][d], j<2048
// ---------------------------------------------------------------------------
__global__ __launch_bounds__(256) void copymem_k(
    const float* __restrict__ mem_k, short* __restrict__ kbuf)
{
    const int total4 = B_ * MEM_ * INNER_ / 4;
    for (int idx = blockIdx.x * blockDim.x + threadIdx.x; idx < total4;
         idx += gridDim.x * blockDim.x) {
        const int flat = idx * 4;
        const int c = flat & 1023;
        const int j = (flat >> 10) & 2047;
        const int b = flat >> 21;
        const int h = c >> 6, d = c & 63;
        float4 v = ((const float4*)mem_k)[idx];
        s16x4 o;
        o[0] = bf16_of(v.x); o[1] = bf16_of(v.y);
        o[2] = bf16_of(v.z); o[3] = bf16_of(v.w);
        *(s16x4*)&kbuf[(((size_t)(b * H_ + h)) * JT_ + j) * DH_ + d] = o;
    }
}

// ---------------------------------------------------------------------------
// Kernel E: mem_v fp32 [b][j][h*64+d] -> vtbuf bf16 [b][h][d][j], j<2048
// ---------------------------------------------------------------------------
__global__ __launch_bounds__(256) void transpose_memv(
    const float* __restrict__ mem_v, short* __restrict__ vtbuf)
{
    const int jt = blockIdx.x, h = blockIdx.y, b = blockIdx.z;
    const int j0 = jt * 64;
    __shared__ float tile[64][65];
    const int t = threadIdx.x;
    const int r = t >> 2, s4 = (t & 3) * 16;
#pragma unroll
    for (int k = 0; k < 4; ++k) {
        float4 v = *(const float4*)&mem_v[((size_t)(b * MEM_ + j0 + r)) * INNER_ + h * DH_ + s4 + k * 4];
        tile[s4 + k * 4 + 0][r] = v.x;
        tile[s4 + k * 4 + 1][r] = v.y;
        tile[s4 + k * 4 + 2][r] = v.z;
        tile[s4 + k * 4 + 3][r] = v.w;
    }
    __syncthreads();
    short ov[16];
#pragma unroll
    for (int e = 0; e < 16; ++e) ov[e] = bf16_of(tile[r][s4 + e]);
    short* dst = &vtbuf[((size_t)((b * H_ + h) * DH_ + r)) * JT_ + j0 + s4];
    *(s16x8*)&dst[0] = *(s16x8*)&ov[0];
    *(s16x8*)&dst[8] = *(s16x8*)&ov[8];
}

// ---------------------------------------------------------------------------
// Kernel F: flash attention, bf16 MFMA. v3:
//  - round-4 shape: 256 threads, 4 waves x 32 q-rows (proven ~195us base)
//  - K/V double-buffer staged via global_load_lds (cannot be compiler-sunk;
//    one __syncthreads per tile, its vmcnt(0) drain lands after full compute)
//  - linear [64][64] LDS + XOR-swizzled global source & ds_read (rule #21,
//    same pattern as mfma_proj; 2-way banks per quarter-wave = free)
//  - bias as MFMA C-in, prefetched one tile ahead (loop-carried regs can't
//    sink across the barrier)
//  - remap: h%8 -> XCD bias/KV sharing; lid vs lid+256 complementary zt
// ---------------------------------------------------------------------------
#define LDP 72

__global__ __launch_bounds__(256) void attn_flash(
    const short* __restrict__ qbuf, const short* __restrict__ kbuf,
    const short* __restrict__ vtbuf, const float* __restrict__ pos_bias,
    float* __restrict__ out)
{
    const int lid = blockIdx.x;                       // 0..511
    const int k_  = lid & 255;
    const int hi  = lid >> 8;
    const int h   = (k_ & 7) | (((k_ >> 3) & 1) << 3);
    const int b   = (k_ >> 4) & 1;
    const int ztl = k_ >> 5;                          // 0..7
    const int zt  = hi ? (15 - ztl) : ztl;            // balanced pairing
    const int i0  = zt * 128;

    const int tid = threadIdx.x;
    const int w = tid >> 6, lane = tid & 63, g = lane >> 4, li = lane & 15;

    __shared__ short K_lds[2][64 * 64];    // linear, chunk-swizzled content
    __shared__ short VT_lds[2][64 * 64];
    __shared__ short P_lds[4][32 * LDP];

    const size_t bh = b * H_ + h;
    const short* kg  = kbuf  + bh * (size_t)JT_ * DH_;
    const short* vtg = vtbuf + bh * (size_t)DH_ * JT_;
    const float* pb  = pos_bias + (size_t)h * N_ * JT_;

    // Q fragments in regs
    s16x8 aq[2][2];
#pragma unroll
    for (int mt = 0; mt < 2; ++mt)
#pragma unroll
        for (int kc = 0; kc < 2; ++kc)
            aq[mt][kc] = *(const s16x8*)&qbuf[(bh * N_ + i0 + w * 32 + mt * 16 + li) * DH_ + kc * 32 + g * 8];

    f32x4 o[2][4];
    float m_run[2][4], l_run[2][4];
#pragma unroll
    for (int mt = 0; mt < 2; ++mt) {
#pragma unroll
        for (int dt = 0; dt < 4; ++dt) o[mt][dt] = f32x4{0.f, 0.f, 0.f, 0.f};
#pragma unroll
        for (int r = 0; r < 4; ++r) { m_run[mt][r] = -3.0e38f; l_run[mt][r] = 0.f; }
    }

    const int ntiles = 34 + 2 * zt;

    // ---- async stage via global_load_lds: buf gets tile at key offset j0s ----
    // dest linear [row][chunk]; source chunk pre-swizzled: qs = q ^ (row&7)
    #define STAGE(bufi, j0s)                                                   \
    {                                                                          \
        _Pragma("unroll")                                                      \
        for (int u = 0; u < 2; ++u) {                                          \
            const int c = u * 256 + tid;                                       \
            const int row = c >> 3, q = c & 7;                                 \
            const int qs = q ^ (row & 7);                                      \
            gload16(&kg[(size_t)((j0s) + row) * DH_ + qs * 8],                 \
                    &K_lds[bufi][c * 8]);                                      \
            gload16(&vtg[(size_t)row * JT_ + (j0s) + qs * 8],                  \
                    &VT_lds[bufi][c * 8]);                                     \
        }                                                                      \
    }

    // bias prefetch regs (loop-carried: cannot sink across barrier)
    float bnext[2][4][4];
    {
        const int qb0 = i0 + w * 32 + g * 4;
#pragma unroll
        for (int mt = 0; mt < 2; ++mt)
#pragma unroll
            for (int nt = 0; nt < 4; ++nt)
#pragma unroll
                for (int r = 0; r < 4; ++r)
                    bnext[mt][nt][r] = pb[(size_t)(qb0 + mt * 16 + r) * JT_ + nt * 16 + li];
    }

    STAGE(0, 0);
    __syncthreads();   // drains vmcnt: tile 0 staged, bias(0) in regs

    for (int t = 0; t < ntiles; ++t) {
        const int cur = t & 1;
        const int j0 = t * 64;

        // issue next tile's staging BEFORE compute (hidden under this tile)
        if (t + 1 < ntiles) STAGE(cur ^ 1, j0 + 64);

        // S = Q K^T with bias as C-in
        f32x4 sacc[2][4];
#pragma unroll
        for (int mt = 0; mt < 2; ++mt)
#pragma unroll
            for (int nt = 0; nt < 4; ++nt)
#pragma unroll
                for (int r = 0; r < 4; ++r)
                    sacc[mt][nt][r] = bnext[mt][nt][r];

        // prefetch bias for tile t+1 (used after the barrier -> latency hidden)
        if (t + 1 < ntiles) {
            const int qb0 = i0 + w * 32 + g * 4;
#pragma unroll
            for (int mt = 0; mt < 2; ++mt)
#pragma unroll
                for (int nt = 0; nt < 4; ++nt)
#pragma unroll
                    for (int r = 0; r < 4; ++r)
                        bnext[mt][nt][r] = pb[(size_t)(qb0 + mt * 16 + r) * JT_ + j0 + 64 + nt * 16 + li];
        }

#pragma unroll
        for (int kc = 0; kc < 2; ++kc)
#pragma unroll
            for (int nt = 0; nt < 4; ++nt) {
                s16x8 bk = *(const s16x8*)&K_lds[cur][(nt * 16 + li) * 64 + ((kc * 4 + g) ^ (li & 7)) * 8];
                sacc[0][nt] = __builtin_amdgcn_mfma_f32_16x16x32_bf16(aq[0][kc], bk, sacc[0][nt], 0, 0, 0);
                sacc[1][nt] = __builtin_amdgcn_mfma_f32_16x16x32_bf16(aq[1][kc], bk, sacc[1][nt], 0, 0, 0);
            }

        // ---- mask + online softmax + P writes ----
#pragma unroll
        for (int mt = 0; mt < 2; ++mt) {
            const int qrb = i0 + w * 32 + mt * 16 + g * 4;   // + r = global i
            float s[4][4];
#pragma unroll
            for (int nt = 0; nt < 4; ++nt) {
                const int jg = j0 + nt * 16 + li;
#pragma unroll
                for (int r = 0; r < 4; ++r)
                    s[nt][r] = (jg > MEM_ + qrb + r) ? -1e30f : sacc[mt][nt][r];
            }
            float sc[4];
#pragma unroll
            for (int r = 0; r < 4; ++r) {
                float tm = fmaxf(fmaxf(s[0][r], s[1][r]), fmaxf(s[2][r], s[3][r]));
                tm = fmaxf(tm, __shfl_xor(tm, 1));
                tm = fmaxf(tm, __shfl_xor(tm, 2));
                tm = fmaxf(tm, __shfl_xor(tm, 4));
                tm = fmaxf(tm, __shfl_xor(tm, 8));
                const float m_new = fmaxf(m_run[mt][r], tm);
                sc[r] = __expf(m_run[mt][r] - m_new);
                m_run[mt][r] = m_new;
            }
#pragma unroll
            for (int nt = 0; nt < 4; ++nt)
#pragma unroll
                for (int r = 0; r < 4; ++r)
                    s[nt][r] = __expf(s[nt][r] - m_run[mt][r]);
#pragma unroll
            for (int r = 0; r < 4; ++r) {
                float ts = s[0][r] + s[1][r] + s[2][r] + s[3][r];
                ts += __shfl_xor(ts, 1);
                ts += __shfl_xor(ts, 2);
                ts += __shfl_xor(ts, 4);
                ts += __shfl_xor(ts, 8);
                l_run[mt][r] = l_run[mt][r] * sc[r] + ts;
#pragma unroll
                for (int dt = 0; dt < 4; ++dt) o[mt][dt][r] *= sc[r];
            }
#pragma unroll
            for (int nt = 0; nt < 4; ++nt)
#pragma unroll
                for (int r = 0; r < 4; ++r)
                    P_lds[w][(mt * 16 + g * 4 + r) * LDP + nt * 16 + li] = bf16_of(s[nt][r]);
        }

        // ---- O += P V ----
#pragma unroll
        for (int kc = 0; kc < 2; ++kc) {
            s16x8 pa0 = *(const s16x8*)&P_lds[w][(0 + li) * LDP + kc * 32 + g * 8];
            s16x8 pa1 = *(const s16x8*)&P_lds[w][(16 + li) * LDP + kc * 32 + g * 8];
#pragma unroll
            for (int dt = 0; dt < 4; ++dt) {
                s16x8 bv = *(const s16x8*)&VT_lds[cur][(dt * 16 + li) * 64 + ((kc * 4 + g) ^ (li & 7)) * 8];
                o[0][dt] = __builtin_amdgcn_mfma_f32_16x16x32_bf16(pa0, bv, o[0][dt], 0, 0, 0);
                o[1][dt] = __builtin_amdgcn_mfma_f32_16x16x32_bf16(pa1, bv, o[1][dt], 0, 0, 0);
            }
        }

        __syncthreads();   // drains vmcnt (tile t+1 staged) + all reads of cur done
    }
    #undef STAGE

    // ---- epilogue: out[b][i][h*64+d] = o / l ----
#pragma unroll
    for (int mt = 0; mt < 2; ++mt) {
#pragma unroll
        for (int r = 0; r < 4; ++r) {
            const int i = i0 + w * 32 + mt * 16 + g * 4 + r;
            const float rinv = 1.0f / l_run[mt][r];
#pragma unroll
            for (int dt = 0; dt < 4; ++dt)
                out[((size_t)(b * N_ + i)) * INNER_ + h * DH_ + dt * 16 + li] = o[mt][dt][r] * rinv;
        }
    }
}

// ---------------------------------------------------------------------------
extern "C" void kernel_launch(void* const* d_in, const int* in_sizes, int n_in,
                              void* d_out, int out_size, void* d_ws, size_t ws_size,
                              hipStream_t stream)
{
    const float* x        = (const float*)d_in[0];
    const float* mem_k    = (const float*)d_in[1];
    const float* mem_v    = (const float*)d_in[2];
    const float* pos_bias = (const float*)d_in[3];
    const float* Wq       = (const float*)d_in[4];
    const float* Wkv      = (const float*)d_in[5];
    float* out = (float*)d_out;

    // workspace layout:
    //   qbuf  bf16  8 MiB   [b][h][i][64]
    //   kbuf  bf16 16 MiB   [b][h][j][64]
    //   vtbuf bf16 16 MiB   [b][h][d][j]
    //   xb    bf16  8 MiB   [4096][1024]
    //   Wt    bf16  6 MiB   [3072][1024]
    char* ws = (char*)d_ws;
    short* qbuf  = (short*)(ws);
    short* kbuf  = (short*)(ws + (8u << 20));
    short* vtbuf = (short*)(ws + (24u << 20));
    short* xb    = (short*)(ws + (40u << 20));
    short* Wt    = (short*)(ws + (48u << 20));

    cast_x<<<2048, 256, 0, stream>>>(x, xb);
    cast_w<<<dim3(16, 48), 256, 0, stream>>>(Wq, Wkv, Wt);
    copymem_k<<<2048, 256, 0, stream>>>(mem_k, kbuf);
    transpose_memv<<<dim3(32, H_, B_), 256, 0, stream>>>(mem_v, vtbuf);

    mfma_proj<<<dim3(24, 32), 256, 0, stream>>>(Wt, xb, qbuf, kbuf, vtbuf);

    attn_flash<<<512, 256, 0, stream>>>(qbuf, kbuf, vtbuf, pos_bias, out);
}

// Round 7
// 263.575 us; speedup vs baseline: 2.0408x; 1.1922x over previous
//
#include <hip/hip_runtime.h>
#include <hip/hip_bf16.h>
#include <cstdint>

// Problem shapes (fixed)
#define B_     2
#define N_     2048
#define DIM_   1024
#define H_     16
#define DH_    64
#define MEM_   2048
#define JT_    4096      // MEM_ + N_
#define INNER_ 1024
#define SCALE_ 0.125f

typedef float f32x4 __attribute__((ext_vector_type(4)));
typedef short s16x8 __attribute__((ext_vector_type(8)));
typedef short s16x4 __attribute__((ext_vector_type(4)));

__device__ __forceinline__ short bf16_of(float f) {
    __hip_bfloat16 h = __float2bfloat16(f);   // RNE
    return *(short*)&h;
}

__device__ __forceinline__ void gload16(const void* g, short* l) {
    __builtin_amdgcn_global_load_lds(
        (const __attribute__((address_space(1))) unsigned int*)g,
        (__attribute__((address_space(3))) unsigned int*)l, 16, 0, 0);
}

// ---------------------------------------------------------------------------
// Kernel A: cast x fp32 [4096][1024] -> xb bf16 (row-major)
// ---------------------------------------------------------------------------
__global__ __launch_bounds__(256) void cast_x(
    const float* __restrict__ x, short* __restrict__ xb)
{
    const int total4 = B_ * N_ * DIM_ / 4;   // 1M
    for (int idx = blockIdx.x * blockDim.x + threadIdx.x; idx < total4;
         idx += gridDim.x * blockDim.x) {
        float4 v = ((const float4*)x)[idx];
        s16x4 o;
        o[0] = bf16_of(v.x); o[1] = bf16_of(v.y);
        o[2] = bf16_of(v.z); o[3] = bf16_of(v.w);
        *(s16x4*)&xb[idx * 4] = o;
    }
}

// ---------------------------------------------------------------------------
// Kernel B: transpose-cast weights -> Wt bf16 [3072][1024], Wt[n][k]=W[k][n].
// SCALE folded into q columns (n<1024).
// ---------------------------------------------------------------------------
__global__ __launch_bounds__(256) void cast_w(
    const float* __restrict__ Wq, const float* __restrict__ Wkv,
    short* __restrict__ Wt)
{
    const int kt = blockIdx.x;   // 0..15
    const int nt = blockIdx.y;   // 0..47
    __shared__ float tile[64][65];   // [n_local][k_local]
    const int t = threadIdx.x;
    const int r = t >> 2, s4 = (t & 3) * 16;

    const int n0 = nt * 64;
    const float* src;
    int ldn, nc0;
    if (n0 < 1024) { src = Wq;  ldn = 1024; nc0 = n0; }
    else           { src = Wkv; ldn = 2048; nc0 = n0 - 1024; }
    const float scale = (n0 < 1024) ? SCALE_ : 1.0f;

#pragma unroll
    for (int kq = 0; kq < 4; ++kq) {
        float4 v = *(const float4*)&src[(size_t)(kt * 64 + r) * ldn + nc0 + s4 + kq * 4];
        tile[s4 + kq * 4 + 0][r] = v.x;
        tile[s4 + kq * 4 + 1][r] = v.y;
        tile[s4 + kq * 4 + 2][r] = v.z;
        tile[s4 + kq * 4 + 3][r] = v.w;
    }
    __syncthreads();
    short ov[16];
#pragma unroll
    for (int e = 0; e < 16; ++e) ov[e] = bf16_of(tile[r][s4 + e] * scale);
    short* dst = &Wt[(size_t)(n0 + r) * 1024 + kt * 64 + s4];
    *(s16x8*)&dst[0] = *(s16x8*)&ov[0];
    *(s16x8*)&dst[8] = *(s16x8*)&ov[8];
}

// ---------------------------------------------------------------------------
// Kernel C: MFMA projection GEMM (unchanged from passing rounds 3-6).
// ---------------------------------------------------------------------------
#define PLDC 152

__global__ __launch_bounds__(256) void mfma_proj(
    const short* __restrict__ Wt, const short* __restrict__ xb,
    short* __restrict__ qbuf, short* __restrict__ kbuf, short* __restrict__ vtbuf)
{
    const int bc = blockIdx.x;
    const int bi = blockIdx.y;
    const int tid = threadIdx.x;
    const int w = tid >> 6, lane = tid & 63, g = lane >> 4, li = lane & 15;
    const int wr = w >> 1, wc = w & 1;

    __shared__ short smem[128 * PLDC];
    short* A_lds = smem;
    short* B_lds = smem + 8192;

    f32x4 acc[4][4];
#pragma unroll
    for (int m = 0; m < 4; ++m)
#pragma unroll
        for (int n = 0; n < 4; ++n) acc[m][n] = f32x4{0.f, 0.f, 0.f, 0.f};

    const size_t arow0 = (size_t)bc * 128;
    const size_t brow0 = (size_t)bi * 128;

    for (int t = 0; t < 16; ++t) {
        __syncthreads();
#pragma unroll
        for (int u = 0; u < 4; ++u) {
            const int c = (w * 4 + u) * 64 + lane;
            const int row = c >> 3, q = c & 7;
            const int qs = q ^ (row & 7);
            gload16(&Wt[(arow0 + row) * 1024 + t * 64 + qs * 8],
                    &A_lds[(w * 4 + u) * 512 + lane * 8]);
            gload16(&xb[(brow0 + row) * 1024 + t * 64 + qs * 8],
                    &B_lds[(w * 4 + u) * 512 + lane * 8]);
        }
        __syncthreads();
#pragma unroll
        for (int kc = 0; kc < 2; ++kc) {
            s16x8 af[4], bf[4];
#pragma unroll
            for (int mt = 0; mt < 4; ++mt) {
                const int row = wr * 64 + mt * 16 + li;
                af[mt] = *(const s16x8*)&A_lds[row * 64 + ((kc * 4 + g) ^ (row & 7)) * 8];
            }
#pragma unroll
            for (int nt = 0; nt < 4; ++nt) {
                const int row = wc * 64 + nt * 16 + li;
                bf[nt] = *(const s16x8*)&B_lds[row * 64 + ((kc * 4 + g) ^ (row & 7)) * 8];
            }
#pragma unroll
            for (int mt = 0; mt < 4; ++mt)
#pragma unroll
                for (int nt = 0; nt < 4; ++nt)
                    acc[mt][nt] = __builtin_amdgcn_mfma_f32_16x16x32_bf16(af[mt], bf[nt], acc[mt][nt], 0, 0, 0);
        }
    }

    __syncthreads();
    const int c0 = bc * 128;
    const int i0g = bi * 128;
    const int b = i0g >> 11;
    const int ii0 = i0g & 2047;

    if (c0 < 2048) {
#pragma unroll
        for (int mt = 0; mt < 4; ++mt)
#pragma unroll
            for (int nt = 0; nt < 4; ++nt) {
                const int i_l = wc * 64 + nt * 16 + li;
                const int c_l = wr * 64 + mt * 16 + g * 4;
                s16x4 v4;
                v4[0] = bf16_of(acc[mt][nt][0]);
                v4[1] = bf16_of(acc[mt][nt][1]);
                v4[2] = bf16_of(acc[mt][nt][2]);
                v4[3] = bf16_of(acc[mt][nt][3]);
                *(s16x4*)&smem[i_l * PLDC + c_l] = v4;
            }
        __syncthreads();
        const bool isq = (c0 < 1024);
#pragma unroll
        for (int u = 0; u < 8; ++u) {
            const int ch = tid + u * 256;
            const int i_l = ch >> 4, seg = ch & 15;
            s16x8 v = *(const s16x8*)&smem[i_l * PLDC + seg * 8];
            const int cg = c0 + seg * 8;
            const int h = (cg >> 6) & 15;
            const int d = cg & 63;
            if (isq)
                *(s16x8*)&qbuf[(((size_t)(b * H_ + h)) * N_ + ii0 + i_l) * DH_ + d] = v;
            else
                *(s16x8*)&kbuf[(((size_t)(b * H_ + h)) * JT_ + MEM_ + ii0 + i_l) * DH_ + d] = v;
        }
    } else {
#pragma unroll
        for (int mt = 0; mt < 4; ++mt)
#pragma unroll
            for (int nt = 0; nt < 4; ++nt) {
                const int i_l = wc * 64 + nt * 16 + li;
                const int c_b = wr * 64 + mt * 16 + g * 4;
#pragma unroll
                for (int r = 0; r < 4; ++r)
                    smem[(c_b + r) * PLDC + i_l] = bf16_of(acc[mt][nt][r]);
            }
        __syncthreads();
#pragma unroll
        for (int u = 0; u < 8; ++u) {
            const int ch = tid + u * 256;
            const int c_l = ch >> 4, seg = ch & 15;
            s16x8 v = *(const s16x8*)&smem[c_l * PLDC + seg * 8];
            const int cv = c0 + c_l - 2048;
            const int h = cv >> 6, d = cv & 63;
            *(s16x8*)&vtbuf[(((size_t)(b * H_ + h)) * DH_ + d) * JT_ + MEM_ + ii0 + seg * 8] = v;
        }
    }
}

// ---------------------------------------------------------------------------
// Kernel D: mem_k fp32 [b][j][h*64+d] -> kbuf bf16 [b][h][j][d], j<2048
// ---------------------------------------------------------------------------
__global__ __launch_bounds__(256) void copymem_k(
    const float* __restrict__ mem_k, short* __restrict__ kbuf)
{
    const int total4 = B_ * MEM_ * INNER_ / 4;
    for (int idx = blockIdx.x * blockDim.x + threadIdx.x; idx < total4;
         idx += gridDim.x * blockDim.x) {
        const int flat = idx * 4;
        const int c = flat & 1023;
        const int j = (flat >> 10) & 2047;
        const int b = flat >> 21;
        const int h = c >> 6, d = c & 63;
        float4 v = ((const float4*)mem_k)[idx];
        s16x4 o;
        o[0] = bf16_of(v.x); o[1] = bf16_of(v.y);
        o[2] = bf16_of(v.z); o[3] = bf16_of(v.w);
        *(s16x4*)&kbuf[(((size_t)(b * H_ + h)) * JT_ + j) * DH_ + d] = o;
    }
}

// ---------------------------------------------------------------------------
// Kernel E: mem_v fp32 [b][j][h*64+d] -> vtbuf bf16 [b][h][d][j], j<2048
// ---------------------------------------------------------------------------
__global__ __launch_bounds__(256) void transpose_memv(
    const float* __restrict__ mem_v, short* __restrict__ vtbuf)
{
    const int jt = blockIdx.x, h = blockIdx.y, b = blockIdx.z;
    const int j0 = jt * 64;
    __shared__ float tile[64][65];
    const int t = threadIdx.x;
    const int r = t >> 2, s4 = (t & 3) * 16;
#pragma unroll
    for (int k = 0; k < 4; ++k) {
        float4 v = *(const float4*)&mem_v[((size_t)(b * MEM_ + j0 + r)) * INNER_ + h * DH_ + s4 + k * 4];
        tile[s4 + k * 4 + 0][r] = v.x;
        tile[s4 + k * 4 + 1][r] = v.y;
        tile[s4 + k * 4 + 2][r] = v.z;
        tile[s4 + k * 4 + 3][r] = v.w;
    }
    __syncthreads();
    short ov[16];
#pragma unroll
    for (int e = 0; e < 16; ++e) ov[e] = bf16_of(tile[r][s4 + e]);
    short* dst = &vtbuf[((size_t)((b * H_ + h) * DH_ + r)) * JT_ + j0 + s4];
    *(s16x8*)&dst[0] = *(s16x8*)&ov[0];
    *(s16x8*)&dst[8] = *(s16x8*)&ov[8];
}

// ---------------------------------------------------------------------------
// Kernel F: flash attention, bf16 MFMA. v4 — SWAPPED operands:
//   S^T = mfma(A=K, B=Q): lane owns (j = nt*16+g*4+r rows, q = li col).
//   Softmax per q is lane-local over 16 regs + only 2 shfl_xor (16,32).
//   Bias loads are f32x4 (r = vector idx), used as MFMA C-in, prefetched
//   one tile ahead. P stored [q][j] as s16x4 b64 writes, read as 2x b64
//   (j-contiguous B-frag). O^T = mfma(A=V^T, B=P): epilogue = float4 stores.
//   Mask applied only on diagonal tiles (wave-uniform skip).
//   Staging: gload_lds double-buffer, XOR-swizzled source (as r6, proven).
// ---------------------------------------------------------------------------
#define LPP 72   // P_lds pitch in shorts (144B rows: 2-way banks, b64-aligned)

__global__ __launch_bounds__(256) void attn_flash(
    const short* __restrict__ qbuf, const short* __restrict__ kbuf,
    const short* __restrict__ vtbuf, const float* __restrict__ pos_bias,
    float* __restrict__ out)
{
    const int lid = blockIdx.x;                       // 0..511
    const int k_  = lid & 255;
    const int hi  = lid >> 8;
    const int h   = (k_ & 7) | (((k_ >> 3) & 1) << 3);
    const int b   = (k_ >> 4) & 1;
    const int ztl = k_ >> 5;                          // 0..7
    const int zt  = hi ? (15 - ztl) : ztl;            // balanced pairing
    const int i0  = zt * 128;

    const int tid = threadIdx.x;
    const int w = tid >> 6, lane = tid & 63, g = lane >> 4, li = lane & 15;

    __shared__ short K_lds[2][64 * 64];    // linear, chunk-swizzled content
    __shared__ short VT_lds[2][64 * 64];
    __shared__ short P_lds[4][32 * LPP];   // per wave: [q=32][j pitch 72]

    const size_t bh = b * H_ + h;
    const short* kg  = kbuf  + bh * (size_t)JT_ * DH_;
    const short* vtg = vtbuf + bh * (size_t)DH_ * JT_;
    const float* pb  = pos_bias + (size_t)h * N_ * JT_;

    const int qw = i0 + w * 32;            // wave's first q row

    // Q fragments (used as B operand; A/B frag layouts are identical)
    s16x8 aq[2][2];
#pragma unroll
    for (int mt = 0; mt < 2; ++mt)
#pragma unroll
        for (int kc = 0; kc < 2; ++kc)
            aq[mt][kc] = *(const s16x8*)&qbuf[(bh * N_ + qw + mt * 16 + li) * DH_ + kc * 32 + g * 8];

    f32x4 o[2][4];
    float m_run[2], l_run[2];
#pragma unroll
    for (int mt = 0; mt < 2; ++mt) {
#pragma unroll
        for (int dt = 0; dt < 4; ++dt) o[mt][dt] = f32x4{0.f, 0.f, 0.f, 0.f};
        m_run[mt] = -3.0e38f; l_run[mt] = 0.f;
    }

    const int ntiles = 34 + 2 * zt;

    #define STAGE(bufi, j0s)                                                   \
    {                                                                          \
        _Pragma("unroll")                                                      \
        for (int u = 0; u < 2; ++u) {                                          \
            const int c = u * 256 + tid;                                       \
            const int row = c >> 3, q = c & 7;                                 \
            const int qs = q ^ (row & 7);                                      \
            gload16(&kg[(size_t)((j0s) + row) * DH_ + qs * 8],                 \
                    &K_lds[bufi][c * 8]);                                      \
            gload16(&vtg[(size_t)row * JT_ + (j0s) + qs * 8],                  \
                    &VT_lds[bufi][c * 8]);                                     \
        }                                                                      \
    }

    // bias prefetch (f32x4: lane (g,li) holds bias[q=qw+mt*16+li][j0+nt*16+g*4 .. +3])
    f32x4 bnext[2][4];
    #define LOADB(j0s)                                                         \
    {                                                                          \
        _Pragma("unroll")                                                      \
        for (int mt = 0; mt < 2; ++mt)                                         \
        _Pragma("unroll")                                                      \
        for (int nt = 0; nt < 4; ++nt)                                         \
            bnext[mt][nt] = *(const f32x4*)&pb[(size_t)(qw + mt * 16 + li) * JT_ + (j0s) + nt * 16 + g * 4]; \
    }

    STAGE(0, 0);
    LOADB(0);
    __syncthreads();   // drains vmcnt: tile 0 staged, bias(0) in regs

    for (int t = 0; t < ntiles; ++t) {
        const int cur = t & 1;
        const int j0 = t * 64;

        // issue next tile's staging BEFORE compute (hidden under this tile)
        if (t + 1 < ntiles) STAGE(cur ^ 1, j0 + 64);

        // S^T = mfma(K, Q) with bias as C-in
        f32x4 sacc[2][4];
#pragma unroll
        for (int mt = 0; mt < 2; ++mt)
#pragma unroll
            for (int nt = 0; nt < 4; ++nt) sacc[mt][nt] = bnext[mt][nt];

        // prefetch bias for tile t+1 (consumed after next barrier)
        if (t + 1 < ntiles) LOADB(j0 + 64);

        __builtin_amdgcn_s_setprio(1);
#pragma unroll
        for (int kc = 0; kc < 2; ++kc)
#pragma unroll
            for (int nt = 0; nt < 4; ++nt) {
                s16x8 bk = *(const s16x8*)&K_lds[cur][(nt * 16 + li) * 64 + ((kc * 4 + g) ^ (li & 7)) * 8];
                sacc[0][nt] = __builtin_amdgcn_mfma_f32_16x16x32_bf16(bk, aq[0][kc], sacc[0][nt], 0, 0, 0);
                sacc[1][nt] = __builtin_amdgcn_mfma_f32_16x16x32_bf16(bk, aq[1][kc], sacc[1][nt], 0, 0, 0);
            }
        __builtin_amdgcn_s_setprio(0);

        // ---- per-mt: mask (diagonal tiles only) + lane-local softmax ----
#pragma unroll
        for (int mt = 0; mt < 2; ++mt) {
            const int q = qw + mt * 16 + li;      // this lane's q row
            if (j0 + 63 > MEM_ + qw + mt * 16) {  // wave-uniform: tile touches diagonal
#pragma unroll
                for (int nt = 0; nt < 4; ++nt)
#pragma unroll
                    for (int r = 0; r < 4; ++r) {
                        const int jg = j0 + nt * 16 + g * 4 + r;
                        if (jg > MEM_ + q) sacc[mt][nt][r] = -1e30f;
                    }
            }
            // max over 16 in-lane values (tree) + 2 shfl across g-groups
            float t0 = fmaxf(fmaxf(sacc[mt][0][0], sacc[mt][0][1]), fmaxf(sacc[mt][0][2], sacc[mt][0][3]));
            float t1 = fmaxf(fmaxf(sacc[mt][1][0], sacc[mt][1][1]), fmaxf(sacc[mt][1][2], sacc[mt][1][3]));
            float t2 = fmaxf(fmaxf(sacc[mt][2][0], sacc[mt][2][1]), fmaxf(sacc[mt][2][2], sacc[mt][2][3]));
            float t3 = fmaxf(fmaxf(sacc[mt][3][0], sacc[mt][3][1]), fmaxf(sacc[mt][3][2], sacc[mt][3][3]));
            float tm = fmaxf(fmaxf(t0, t1), fmaxf(t2, t3));
            tm = fmaxf(tm, __shfl_xor(tm, 16));
            tm = fmaxf(tm, __shfl_xor(tm, 32));
            const float m_new = fmaxf(m_run[mt], tm);
            const float sc = __expf(m_run[mt] - m_new);
            m_run[mt] = m_new;

#pragma unroll
            for (int nt = 0; nt < 4; ++nt)
#pragma unroll
                for (int r = 0; r < 4; ++r)
                    sacc[mt][nt][r] = __expf(sacc[mt][nt][r] - m_new);

            float s0 = (sacc[mt][0][0] + sacc[mt][0][1]) + (sacc[mt][0][2] + sacc[mt][0][3]);
            float s1 = (sacc[mt][1][0] + sacc[mt][1][1]) + (sacc[mt][1][2] + sacc[mt][1][3]);
            float s2 = (sacc[mt][2][0] + sacc[mt][2][1]) + (sacc[mt][2][2] + sacc[mt][2][3]);
            float s3 = (sacc[mt][3][0] + sacc[mt][3][1]) + (sacc[mt][3][2] + sacc[mt][3][3]);
            float ts = (s0 + s1) + (s2 + s3);
            ts += __shfl_xor(ts, 16);
            ts += __shfl_xor(ts, 32);
            l_run[mt] = l_run[mt] * sc + ts;
#pragma unroll
            for (int dt = 0; dt < 4; ++dt) o[mt][dt] *= sc;

            // P store: [q=mt*16+li][j = nt*16+g*4 .. +3] as b64
#pragma unroll
            for (int nt = 0; nt < 4; ++nt) {
                s16x4 pk;
                pk[0] = bf16_of(sacc[mt][nt][0]);
                pk[1] = bf16_of(sacc[mt][nt][1]);
                pk[2] = bf16_of(sacc[mt][nt][2]);
                pk[3] = bf16_of(sacc[mt][nt][3]);
                *(s16x4*)&P_lds[w][(mt * 16 + li) * LPP + nt * 16 + g * 4] = pk;
            }
        }

        // ---- O^T += mfma(A=V^T, B=P) ----
        __builtin_amdgcn_s_setprio(1);
#pragma unroll
        for (int kc = 0; kc < 2; ++kc) {
            s16x8 pf[2];
#pragma unroll
            for (int mt = 0; mt < 2; ++mt) {
                s16x4 plo = *(const s16x4*)&P_lds[w][(mt * 16 + li) * LPP + kc * 32 + g * 8];
                s16x4 phi = *(const s16x4*)&P_lds[w][(mt * 16 + li) * LPP + kc * 32 + g * 8 + 4];
#pragma unroll
                for (int e = 0; e < 4; ++e) { pf[mt][e] = plo[e]; pf[mt][4 + e] = phi[e]; }
            }
#pragma unroll
            for (int dt = 0; dt < 4; ++dt) {
                s16x8 bv = *(const s16x8*)&VT_lds[cur][(dt * 16 + li) * 64 + ((kc * 4 + g) ^ (li & 7)) * 8];
                o[0][dt] = __builtin_amdgcn_mfma_f32_16x16x32_bf16(bv, pf[0], o[0][dt], 0, 0, 0);
                o[1][dt] = __builtin_amdgcn_mfma_f32_16x16x32_bf16(bv, pf[1], o[1][dt], 0, 0, 0);
            }
        }
        __builtin_amdgcn_s_setprio(0);

        __syncthreads();   // drains vmcnt (tile t+1 staged); all reads of cur done
    }
    #undef STAGE
    #undef LOADB

    // ---- epilogue: out[b][q][h*64 + dt*16+g*4 .. +3] = o/l, float4 stores ----
#pragma unroll
    for (int mt = 0; mt < 2; ++mt) {
        const float rinv = 1.0f / l_run[mt];
        const int q = qw + mt * 16 + li;
#pragma unroll
        for (int dt = 0; dt < 4; ++dt) {
            f32x4 ov = o[mt][dt] * rinv;
            *(f32x4*)&out[((size_t)(b * N_ + q)) * INNER_ + h * DH_ + dt * 16 + g * 4] = ov;
        }
    }
}

// ---------------------------------------------------------------------------
extern "C" void kernel_launch(void* const* d_in, const int* in_sizes, int n_in,
                              void* d_out, int out_size, void* d_ws, size_t ws_size,
                              hipStream_t stream)
{
    const float* x        = (const float*)d_in[0];
    const float* mem_k    = (const float*)d_in[1];
    const float* mem_v    = (const float*)d_in[2];
    const float* pos_bias = (const float*)d_in[3];
    const float* Wq       = (const float*)d_in[4];
    const float* Wkv      = (const float*)d_in[5];
    float* out = (float*)d_out;

    // workspace layout:
    //   qbuf  bf16  8 MiB   [b][h][i][64]
    //   kbuf  bf16 16 MiB   [b][h][j][64]
    //   vtbuf bf16 16 MiB   [b][h][d][j]
    //   xb    bf16  8 MiB   [4096][1024]
    //   Wt    bf16  6 MiB   [3072][1024]
    char* ws = (char*)d_ws;
    short* qbuf  = (short*)(ws);
    short* kbuf  = (short*)(ws + (8u << 20));
    short* vtbuf = (short*)(ws + (24u << 20));
    short* xb    = (short*)(ws + (40u << 20));
    short* Wt    = (short*)(ws + (48u << 20));

    cast_x<<<2048, 256, 0, stream>>>(x, xb);
    cast_w<<<dim3(16, 48), 256, 0, stream>>>(Wq, Wkv, Wt);
    copymem_k<<<2048, 256, 0, stream>>>(mem_k, kbuf);
    transpose_memv<<<dim3(32, H_, B_), 256, 0, stream>>>(mem_v, vtbuf);

    mfma_proj<<<dim3(24, 32), 256, 0, stream>>>(Wt, xb, qbuf, kbuf, vtbuf);

    attn_flash<<<512, 256, 0, stream>>>(qbuf, kbuf, vtbuf, pos_bias, out);
}